// Round 1
// baseline (130.787 us; speedup 1.0000x reference)
//
#include <hip/hip_runtime.h>

typedef __bf16 bf16_t;
typedef bf16_t bf16x8 __attribute__((ext_vector_type(8)));
typedef bf16_t bf16x4 __attribute__((ext_vector_type(4)));
typedef float f32x4 __attribute__((ext_vector_type(4)));

// ---------------- fp32 -> bf16 convert (vectorized) ----------------
__global__ void f2b_kernel(const float* __restrict__ in, bf16_t* __restrict__ out, int n4) {
    int i = blockIdx.x * blockDim.x + threadIdx.x;
    if (i >= n4) return;
    float4 v = reinterpret_cast<const float4*>(in)[i];
    bf16x4 o = { (bf16_t)v.x, (bf16_t)v.y, (bf16_t)v.z, (bf16_t)v.w };
    reinterpret_cast<bf16x4*>(out)[i] = o;
}

// ---------------- generic bf16 GEMM: C = alpha * A * B^T (+bias) ----------------
// A: [M x K] bf16 row-major (lda), B: [N x K] bf16 row-major (ldb), C: OUT_T (ldc)
// 64x64 tile, 4 waves, MFMA 16x16x32 bf16.
// batching: block z -> (bo, bh) = (z / batchH, z % batchH), operand offsets via strides.
template <typename OUT_T, bool HAS_BIAS>
__global__ __launch_bounds__(256) void gemm_bt(
    const bf16_t* __restrict__ A, const bf16_t* __restrict__ B,
    OUT_T* __restrict__ C, const float* __restrict__ bias,
    int K, int lda, int ldb, int ldc,
    int batchH, long sAb, long sAh, long sBb, long sBh, long sCb, long sCh,
    float alpha)
{
    const int bz = blockIdx.z;
    const int bo = bz / batchH;
    const int bh = bz - bo * batchH;
    A += bo * sAb + bh * sAh;
    B += bo * sBb + bh * sBh;
    C += bo * sCb + bh * sCh;

    const int m0 = blockIdx.x * 64;
    const int n0 = blockIdx.y * 64;

    __shared__ __align__(16) bf16_t As[64][32];
    __shared__ __align__(16) bf16_t Bs[64][32];

    const int tid  = threadIdx.x;
    const int lane = tid & 63;
    const int wave = tid >> 6;
    const int r    = tid >> 2;        // 0..63 staging row
    const int ko   = (tid & 3) * 8;   // 0,8,16,24 staging k-offset

    f32x4 acc[4] = {};

    for (int k0 = 0; k0 < K; k0 += 32) {
        *reinterpret_cast<uint4*>(&As[r][ko]) =
            *reinterpret_cast<const uint4*>(&A[(long)(m0 + r) * lda + k0 + ko]);
        *reinterpret_cast<uint4*>(&Bs[r][ko]) =
            *reinterpret_cast<const uint4*>(&B[(long)(n0 + r) * ldb + k0 + ko]);
        __syncthreads();

        bf16x8 af = *reinterpret_cast<const bf16x8*>(&As[wave * 16 + (lane & 15)][(lane >> 4) * 8]);
#pragma unroll
        for (int nf = 0; nf < 4; ++nf) {
            bf16x8 bfr = *reinterpret_cast<const bf16x8*>(&Bs[nf * 16 + (lane & 15)][(lane >> 4) * 8]);
            acc[nf] = __builtin_amdgcn_mfma_f32_16x16x32_bf16(af, bfr, acc[nf], 0, 0, 0);
        }
        __syncthreads();
    }

    const int crow0 = m0 + wave * 16 + (lane >> 4) * 4;
    const int ccol0 = n0 + (lane & 15);
#pragma unroll
    for (int nf = 0; nf < 4; ++nf) {
        const int col = ccol0 + nf * 16;
        const float bv = HAS_BIAS ? bias[col] : 0.0f;
#pragma unroll
        for (int v = 0; v < 4; ++v) {
            float val = acc[nf][v] * alpha + bv;
            C[(long)(crow0 + v) * ldc + col] = (OUT_T)val;
        }
    }
}

// ---------------- row softmax, in place, 256 cols, 1 wave per row ----------------
__global__ void softmax_rows(float* __restrict__ S) {
    const long row = blockIdx.x;
    float* p = S + row * 256;
    const int lane = threadIdx.x;
    float4 v = reinterpret_cast<float4*>(p)[lane];
    float m = fmaxf(fmaxf(v.x, v.y), fmaxf(v.z, v.w));
#pragma unroll
    for (int off = 32; off > 0; off >>= 1) m = fmaxf(m, __shfl_xor(m, off));
    float e0 = __expf(v.x - m), e1 = __expf(v.y - m), e2 = __expf(v.z - m), e3 = __expf(v.w - m);
    float l = e0 + e1 + e2 + e3;
#pragma unroll
    for (int off = 32; off > 0; off >>= 1) l += __shfl_xor(l, off);
    const float inv = 1.0f / l;
    float4 o; o.x = e0 * inv; o.y = e1 * inv; o.z = e2 * inv; o.w = e3 * inv;
    reinterpret_cast<float4*>(p)[lane] = o;
}

// ---------------- fused: oh[b,i,c] = sum_j attn[b,h(c),i,j] * (v[b,j,c] + d[b,i,j,c]) ----------------
// grid: (B*N, 3) blocks of 256 threads; each block handles one (b,i) and a 256-col chunk (4 heads).
__global__ __launch_bounds__(256) void attnd_kernel(
    const float* __restrict__ attn,   // [B*12, 256, 256]
    const bf16_t* __restrict__ qkv,   // [B, 256, 2304] bf16
    const float* __restrict__ d,      // [B, 256, 256, 768]
    bf16_t* __restrict__ oh)          // [B, 256, 768] bf16
{
    const int bi = blockIdx.x;          // b*256 + i
    const int b  = bi >> 8;
    const int i  = bi & 255;
    const int cc = blockIdx.y;          // 0..2
    const int t  = threadIdx.x;
    const int c  = cc * 256 + t;

    __shared__ float attn_s[1024];      // 4 heads x 256 j
    const int h0 = cc * 4;
#pragma unroll
    for (int q = 0; q < 4; ++q) {
        attn_s[q * 256 + t] = attn[(((long)(b * 12 + h0 + q) * 256) + i) * 256 + t];
    }
    __syncthreads();

    const float* arow = attn_s + ((t >> 6) << 8);          // this thread's head row
    const float* dp   = d + (long)bi * 196608 + c;          // d[b,i,0,c]
    const bf16_t* vp  = qkv + (long)b * 589824 + 1536 + c;  // v[b,0,c]

    float acc = 0.0f;
#pragma unroll 8
    for (int j = 0; j < 256; ++j) {
        float dv = dp[(long)j * 768];
        float vv = (float)vp[(long)j * 2304];
        acc = fmaf(arow[j], dv + vv, acc);
    }
    oh[(long)bi * 768 + c] = (bf16_t)acc;
}

// ---------------- launch ----------------
extern "C" void kernel_launch(void* const* d_in, const int* in_sizes, int n_in,
                              void* d_out, int out_size, void* d_ws, size_t ws_size,
                              hipStream_t stream) {
    const float* x      = (const float*)d_in[0];   // [2,256,768]
    const float* d      = (const float*)d_in[1];   // [2,256,256,768]
    const float* w_qkv  = (const float*)d_in[2];   // [2304,768]
    const float* w_proj = (const float*)d_in[3];   // [768,768]
    const float* b_proj = (const float*)d_in[4];   // [768]
    float* out = (float*)d_out;                    // [2,256,768]

    char* ws = (char*)d_ws;
    bf16_t* xb   = (bf16_t*)(ws);                  //  512x768
    bf16_t* wqb  = (bf16_t*)(ws + 786432);         // 2304x768
    bf16_t* wpb  = (bf16_t*)(ws + 4325376);        //  768x768
    bf16_t* qkvb = (bf16_t*)(ws + 5505024);        //  512x2304
    float*  S    = (float*)(ws + 7864320);         //  24x256x256 fp32
    bf16_t* oh   = (bf16_t*)(ws + 14155776);       //  512x768

    // converts
    f2b_kernel<<<393216 / 1024, 256, 0, stream>>>(x, xb, 393216 / 4);
    f2b_kernel<<<1769472 / 1024, 256, 0, stream>>>(w_qkv, wqb, 1769472 / 4);
    f2b_kernel<<<589824 / 1024, 256, 0, stream>>>(w_proj, wpb, 589824 / 4);

    // qkv = x @ w_qkv^T  -> bf16 [512,2304]
    gemm_bt<bf16_t, false><<<dim3(8, 36, 1), 256, 0, stream>>>(
        xb, wqb, qkvb, nullptr, 768, 768, 768, 2304,
        1, 0, 0, 0, 0, 0, 0, 1.0f);

    // S[b,h] = (q/8) @ k^T  -> fp32 [24,256,256]
    gemm_bt<float, false><<<dim3(4, 4, 24), 256, 0, stream>>>(
        qkvb, qkvb + 768, S, nullptr, 64, 2304, 2304, 256,
        12, 589824, 64, 589824, 64, 786432, 65536, 0.125f);

    // softmax rows in place
    softmax_rows<<<6144, 64, 0, stream>>>(S);

    // oh = attn @ (v + d_pair)  -> bf16 [512,768]
    attnd_kernel<<<dim3(512, 3, 1), 256, 0, stream>>>(S, qkvb, d, oh);

    // out = oh @ w_proj^T + b_proj -> fp32
    gemm_bt<float, true><<<dim3(8, 12, 1), 256, 0, stream>>>(
        oh, wpb, out, b_proj, 768, 768, 768, 768,
        1, 0, 0, 0, 0, 0, 0, 1.0f);
}

// Round 3
// 119.875 us; speedup vs baseline: 1.0910x; 1.0910x over previous
//
#include <hip/hip_runtime.h>

typedef __bf16 bf16_t;
typedef bf16_t bf16x8 __attribute__((ext_vector_type(8)));
typedef bf16_t bf16x4 __attribute__((ext_vector_type(4)));
typedef float f32x4 __attribute__((ext_vector_type(4)));

// ---------------- fp32 -> bf16 convert, all three tensors in one launch ----------------
// ranges (float4 units): x 98304 | w_qkv 442368 | w_proj 147456  (total 688128 = 2688*256)
__global__ void f2b_all(const float* __restrict__ x, const float* __restrict__ wq,
                        const float* __restrict__ wp,
                        bf16_t* __restrict__ xb, bf16_t* __restrict__ wqb,
                        bf16_t* __restrict__ wpb) {
    int i = blockIdx.x * blockDim.x + threadIdx.x;
    const float* src; bf16_t* dst; int off;
    if (i < 98304)       { src = x;  dst = xb;  off = i; }
    else if (i < 540672) { src = wq; dst = wqb; off = i - 98304; }
    else                 { src = wp; dst = wpb; off = i - 540672; }
    f32x4 v = reinterpret_cast<const f32x4*>(src)[off];
    bf16x4 o = { (bf16_t)v[0], (bf16_t)v[1], (bf16_t)v[2], (bf16_t)v[3] };
    reinterpret_cast<bf16x4*>(dst)[off] = o;
}

// ---------------- bf16 GEMM: C = A * B^T (+bias), 64x64 tile, BK=64, padded LDS ----------------
// A: [M x K] bf16 (lda), B: [N x K] bf16 (ldb). K % 64 == 0.
template <typename OUT_T, bool HAS_BIAS>
__global__ __launch_bounds__(256) void gemm_bt(
    const bf16_t* __restrict__ A, const bf16_t* __restrict__ B,
    OUT_T* __restrict__ C, const float* __restrict__ bias,
    int K, int lda, int ldb, int ldc)
{
    const int m0 = blockIdx.x * 64;
    const int n0 = blockIdx.y * 64;

    __shared__ __align__(16) bf16_t As[64][72];   // +8 pad: row stride 144B -> 2-way bank alias (free)
    __shared__ __align__(16) bf16_t Bs[64][72];

    const int tid  = threadIdx.x;
    const int lane = tid & 63;
    const int wave = tid >> 6;

    f32x4 acc[4] = {};

    for (int k0 = 0; k0 < K; k0 += 64) {
#pragma unroll
        for (int c = 0; c < 2; ++c) {
            const int chunk = c * 256 + tid;       // 512 chunks of 16B per tile
            const int row = chunk >> 3;
            const int off = (chunk & 7) * 8;
            *reinterpret_cast<uint4*>(&As[row][off]) =
                *reinterpret_cast<const uint4*>(&A[(long)(m0 + row) * lda + k0 + off]);
            *reinterpret_cast<uint4*>(&Bs[row][off]) =
                *reinterpret_cast<const uint4*>(&B[(long)(n0 + row) * ldb + k0 + off]);
        }
        __syncthreads();
#pragma unroll
        for (int ks = 0; ks < 64; ks += 32) {
            bf16x8 af = *reinterpret_cast<const bf16x8*>(&As[wave * 16 + (lane & 15)][(lane >> 4) * 8 + ks]);
#pragma unroll
            for (int nf = 0; nf < 4; ++nf) {
                bf16x8 bfr = *reinterpret_cast<const bf16x8*>(&Bs[nf * 16 + (lane & 15)][(lane >> 4) * 8 + ks]);
                acc[nf] = __builtin_amdgcn_mfma_f32_16x16x32_bf16(af, bfr, acc[nf], 0, 0, 0);
            }
        }
        __syncthreads();
    }

    const int crow0 = m0 + wave * 16 + (lane >> 4) * 4;
    const int ccol0 = n0 + (lane & 15);
#pragma unroll
    for (int nf = 0; nf < 4; ++nf) {
        const int col = ccol0 + nf * 16;
        const float bv = HAS_BIAS ? bias[col] : 0.0f;
#pragma unroll
        for (int v = 0; v < 4; ++v) {
            C[(long)(crow0 + v) * ldc + col] = (OUT_T)(acc[nf][v] + bv);
        }
    }
}

// ---------------- fused S = softmax((q/8) k^T): one block = 64 rows x 256 cols of one (b,h) ----------------
__global__ __launch_bounds__(256) void qk_softmax(
    const bf16_t* __restrict__ qkv,   // [B,256,2304]
    float* __restrict__ probs)        // [24,256,256]
{
    const int bh = blockIdx.y;                 // b*12 + h
    const int b = bh / 12, h = bh % 12;
    const int m0 = blockIdx.x * 64;
    const bf16_t* qbase = qkv + (long)b * 589824 + h * 64;
    const bf16_t* kbase = qkv + (long)b * 589824 + 768 + h * 64;

    __shared__ __align__(16) bf16_t Qs[64][72];
    __shared__ __align__(16) bf16_t Ks[256][72];

    const int t = threadIdx.x;
#pragma unroll
    for (int c = 0; c < 2; ++c) {              // Q: 64 rows x 8 chunks
        const int chunk = c * 256 + t;
        const int row = chunk >> 3, off = (chunk & 7) * 8;
        *reinterpret_cast<uint4*>(&Qs[row][off]) =
            *reinterpret_cast<const uint4*>(qbase + (long)(m0 + row) * 2304 + off);
    }
#pragma unroll
    for (int c = 0; c < 8; ++c) {              // K: 256 rows x 8 chunks
        const int chunk = c * 256 + t;
        const int row = chunk >> 3, off = (chunk & 7) * 8;
        *reinterpret_cast<uint4*>(&Ks[row][off]) =
            *reinterpret_cast<const uint4*>(kbase + (long)row * 2304 + off);
    }
    __syncthreads();

    const int lane = t & 63, wave = t >> 6;
    f32x4 acc[16] = {};
#pragma unroll
    for (int ks = 0; ks < 64; ks += 32) {
        bf16x8 af = *reinterpret_cast<const bf16x8*>(&Qs[wave * 16 + (lane & 15)][(lane >> 4) * 8 + ks]);
#pragma unroll
        for (int nf = 0; nf < 16; ++nf) {
            bf16x8 bfr = *reinterpret_cast<const bf16x8*>(&Ks[nf * 16 + (lane & 15)][(lane >> 4) * 8 + ks]);
            acc[nf] = __builtin_amdgcn_mfma_f32_16x16x32_bf16(af, bfr, acc[nf], 0, 0, 0);
        }
    }

    // scale, then row softmax. Row r is held by the 16 lanes sharing (lane>>4):
    // value (nf, v) = S[row = wave*16 + (lane>>4)*4 + v][col = nf*16 + (lane&15)]
    float inv[4];
#pragma unroll
    for (int v = 0; v < 4; ++v) {
        float mm = -1e30f;
#pragma unroll
        for (int nf = 0; nf < 16; ++nf) { acc[nf][v] *= 0.125f; mm = fmaxf(mm, acc[nf][v]); }
#pragma unroll
        for (int o = 1; o < 16; o <<= 1) mm = fmaxf(mm, __shfl_xor(mm, o));
        float s = 0.0f;
#pragma unroll
        for (int nf = 0; nf < 16; ++nf) { float e = __expf(acc[nf][v] - mm); acc[nf][v] = e; s += e; }
#pragma unroll
        for (int o = 1; o < 16; o <<= 1) s += __shfl_xor(s, o);
        inv[v] = 1.0f / s;
    }

    float* prow = probs + ((long)bh * 256 + m0 + wave * 16 + (lane >> 4) * 4) * 256 + (lane & 15);
#pragma unroll
    for (int nf = 0; nf < 16; ++nf) {
#pragma unroll
        for (int v = 0; v < 4; ++v) {
            prow[(long)v * 256 + nf * 16] = acc[nf][v] * inv[v];
        }
    }
}

// ---------------- fused: oh[b,i,c] = sum_j attn[b,h(c),i,j] * (v[b,j,c] + d[b,i,j,c]) ----------------
// grid (512, 3) x 256 threads. Block = one (b,i), one 256-col chunk. Wave w owns j in [w*64, w*64+64).
__global__ __launch_bounds__(256) void attnd_kernel(
    const float* __restrict__ attn,   // [24,256,256] fp32 probs
    const bf16_t* __restrict__ qkv,   // [B,256,2304]
    const float* __restrict__ d,      // [B,256,256,768]
    bf16_t* __restrict__ oh)          // [B,256,768]
{
    const int bi = blockIdx.x;          // b*256 + i
    const int b  = bi >> 8;
    const int i  = bi & 255;
    const int cc = blockIdx.y;          // 0..2
    const int t  = threadIdx.x;
    const int lane = t & 63, wave = t >> 6;

    __shared__ float attn_s[4 * 257];           // 4 heads x 256 j, padded
    __shared__ f32x4 partial[3][64];

#pragma unroll
    for (int q = 0; q < 4; ++q) {
        attn_s[q * 257 + t] = attn[(((long)(b * 12 + cc * 4 + q)) * 256 + i) * 256 + t];
    }
    __syncthreads();

    const int c0 = cc * 256 + lane * 4;
    const float* arow = attn_s + (lane >> 4) * 257;   // this lane's head row
    const int jb = wave * 64;
    const f32x4* dp = reinterpret_cast<const f32x4*>(d + (long)bi * 196608 + (long)jb * 768 + c0);
    const bf16_t* vp = qkv + (long)b * 589824 + (long)jb * 2304 + 1536 + c0;

    f32x4 acc = {};
#pragma unroll 8
    for (int jj = 0; jj < 64; ++jj) {
        f32x4 dv = __builtin_nontemporal_load(dp + (long)jj * 192);
        bf16x4 vv = *reinterpret_cast<const bf16x4*>(vp + (long)jj * 2304);
        float a = arow[jb + jj];
        acc[0] = fmaf(a, dv[0] + (float)vv[0], acc[0]);
        acc[1] = fmaf(a, dv[1] + (float)vv[1], acc[1]);
        acc[2] = fmaf(a, dv[2] + (float)vv[2], acc[2]);
        acc[3] = fmaf(a, dv[3] + (float)vv[3], acc[3]);
    }

    if (wave) partial[wave - 1][lane] = acc;
    __syncthreads();
    if (wave == 0) {
        acc += partial[0][lane] + partial[1][lane] + partial[2][lane];
        bf16x4 o = { (bf16_t)acc[0], (bf16_t)acc[1], (bf16_t)acc[2], (bf16_t)acc[3] };
        *reinterpret_cast<bf16x4*>(oh + (long)bi * 768 + c0) = o;
    }
}

// ---------------- launch ----------------
extern "C" void kernel_launch(void* const* d_in, const int* in_sizes, int n_in,
                              void* d_out, int out_size, void* d_ws, size_t ws_size,
                              hipStream_t stream) {
    const float* x      = (const float*)d_in[0];   // [2,256,768]
    const float* d      = (const float*)d_in[1];   // [2,256,256,768]
    const float* w_qkv  = (const float*)d_in[2];   // [2304,768]
    const float* w_proj = (const float*)d_in[3];   // [768,768]
    const float* b_proj = (const float*)d_in[4];   // [768]
    float* out = (float*)d_out;                    // [2,256,768]

    char* ws = (char*)d_ws;
    bf16_t* xb    = (bf16_t*)(ws);                  //  512x768
    bf16_t* wqb   = (bf16_t*)(ws + 786432);         // 2304x768
    bf16_t* wpb   = (bf16_t*)(ws + 4325376);        //  768x768
    bf16_t* qkvb  = (bf16_t*)(ws + 5505024);        //  512x2304
    float*  probs = (float*)(ws + 7864320);         //  24x256x256 fp32
    bf16_t* oh    = (bf16_t*)(ws + 14155776);       //  512x768

    // 1. converts (one launch)
    f2b_all<<<2688, 256, 0, stream>>>(x, w_qkv, w_proj, xb, wqb, wpb);

    // 2. qkv = x @ w_qkv^T -> bf16 [512,2304]
    gemm_bt<bf16_t, false><<<dim3(8, 36), 256, 0, stream>>>(
        xb, wqb, qkvb, nullptr, 768, 768, 768, 2304);

    // 3. probs = softmax((q/8) k^T) -> fp32 [24,256,256]
    qk_softmax<<<dim3(4, 24), 256, 0, stream>>>(qkvb, probs);

    // 4. oh = attn @ (v + d_pair) -> bf16 [512,768]
    attnd_kernel<<<dim3(512, 3), 256, 0, stream>>>(probs, qkvb, d, oh);

    // 5. out = oh @ w_proj^T + b_proj -> fp32
    gemm_bt<float, true><<<dim3(8, 12), 256, 0, stream>>>(
        oh, wpb, out, b_proj, 768, 768, 768, 768);
}